// Round 1
// baseline (272.231 us; speedup 1.0000x reference)
//
#include <hip/hip_runtime.h>

typedef unsigned short u16;
typedef unsigned int u32;
typedef __bf16 bf16x8 __attribute__((ext_vector_type(8)));
typedef float f32x4 __attribute__((ext_vector_type(4)));

#define T_ 5000

__device__ __forceinline__ u16 f2bf(float f) {
  u32 u = __float_as_uint(f);
  u += 0x7fffu + ((u >> 16) & 1u);
  return (u16)(u >> 16);
}
__device__ __forceinline__ float bf2f(u32 bits16) {
  return __uint_as_float(bits16 << 16);
}

__device__ __forceinline__ void gload_lds16(const u16* g, u16* l) {
  __builtin_amdgcn_global_load_lds(
      (__attribute__((address_space(1))) void*)(u16*)g,
      (__attribute__((address_space(3))) void*)l, 16, 0, 0);
}

// f32 [Z][512][512] -> bf16 [Z][512][512] transposed: dst[z][b][a] = src[z][a][b]
__global__ void transpose_cast(const float* __restrict__ src, u16* __restrict__ dst) {
  __shared__ float tile[32][33];
  const int tx = threadIdx.x, ty = threadIdx.y;
  const int a0 = blockIdx.x * 32;
  const int b0 = blockIdx.y * 32;
  const size_t zoff = (size_t)blockIdx.z * (512 * 512);
  const float* s = src + zoff;
  u16* d = dst + zoff;
#pragma unroll
  for (int r = 0; r < 4; ++r)
    tile[ty + r * 8][tx] = s[(size_t)(a0 + ty + r * 8) * 512 + b0 + tx];
  __syncthreads();
#pragma unroll
  for (int r = 0; r < 4; ++r)
    d[(size_t)(b0 + ty + r * 8) * 512 + a0 + tx] = f2bf(tile[tx][ty + r * 8]);
}

// dg[b,j] = ui[(ev-1)*(T+1)]
__global__ void diag_k(const int* __restrict__ ev, const float* __restrict__ ui,
                       float* __restrict__ dg) {
  const int t = blockIdx.x * 256 + threadIdx.x;
  const long r = (long)ev[t] - 1;
  dg[t] = ui[r * (long)(T_ + 1)];
}

// adj[b][i][j] = bf16( ui[ri*T + rj] + dg[b,j] ); one block per (b,i) row
__global__ void gather_adj(const int* __restrict__ ev, const float* __restrict__ ui,
                           const float* __restrict__ dg, u16* __restrict__ adj) {
  const int bi = blockIdx.x;       // b*512 + i
  const int b = bi >> 9;
  const long ri = (long)ev[bi] - 1;
  const float* __restrict__ row = ui + ri * (long)T_;
  const int j = threadIdx.x * 2;
  const int base = (b << 9) + j;
  const int rj0 = ev[base] - 1;
  const int rj1 = ev[base + 1] - 1;
  const float v0 = row[rj0] + dg[base];
  const float v1 = row[rj1] + dg[base + 1];
  const u32 pk = (u32)f2bf(v0) | ((u32)f2bf(v1) << 16);
  *(u32*)&adj[(size_t)bi * 512 + j] = pk;
}

// C = A @ B, A: [batch][512][512] bf16 row-major, Bm: [batch][512][512] bf16,
// stored TRANSPOSED (Bm[n][k] = B[k][n]).
// MODE 0: C row-major bf16.  MODE 1: C transposed (Cb[n][m]) + relu, bf16.
// 128x128 tile, BK=32, 4 waves (2x2), each wave 64x64 = 4x4 mfma_16x16x32 frags.
template <int MODE>
__global__ __launch_bounds__(256)
void gemm_bt(const u16* __restrict__ A, const u16* __restrict__ Bm,
             u16* __restrict__ C, size_t strideA, size_t strideB, size_t strideC) {
  __shared__ u16 sA[128 * 32];
  __shared__ u16 sB[128 * 32];
  const int tid = threadIdx.x;
  const int lane = tid & 63;
  const int w = tid >> 6;
  const int m0 = (blockIdx.x >> 2) * 128;
  const int n0 = (blockIdx.x & 3) * 128;
  const u16* Ab = A + (size_t)blockIdx.y * strideA;
  const u16* Bb = Bm + (size_t)blockIdx.y * strideB;
  u16* Cb = C + (size_t)blockIdx.y * strideC;
  const int wr = (w >> 1) * 64;
  const int wc = (w & 1) * 64;
  const int lr = lane & 15;
  const int lk = (lane >> 4) * 8;
  f32x4 acc[4][4] = {};

  for (int k0 = 0; k0 < 512; k0 += 32) {
    __syncthreads();
    // stage A,B tiles: 128x32 bf16 = 512 chunks of 16B each; 2 issues/thread/tile
#pragma unroll
    for (int q = 0; q < 2; ++q) {
      const int cb = q * 256 + w * 64;  // wave-uniform chunk base
      const int c = cb + lane;          // this lane's chunk
      gload_lds16(Ab + (size_t)(m0 + (c >> 2)) * 512 + k0 + (c & 3) * 8, &sA[cb * 8]);
      gload_lds16(Bb + (size_t)(n0 + (c >> 2)) * 512 + k0 + (c & 3) * 8, &sB[cb * 8]);
    }
    __syncthreads();  // compiler drains vmcnt before s_barrier

    bf16x8 a[4], b[4];
#pragma unroll
    for (int m = 0; m < 4; ++m)
      a[m] = *(const bf16x8*)&sA[(wr + m * 16 + lr) * 32 + lk];
#pragma unroll
    for (int n = 0; n < 4; ++n)
      b[n] = *(const bf16x8*)&sB[(wc + n * 16 + lr) * 32 + lk];
#pragma unroll
    for (int m = 0; m < 4; ++m)
#pragma unroll
      for (int n = 0; n < 4; ++n)
        acc[m][n] = __builtin_amdgcn_mfma_f32_16x16x32_bf16(a[m], b[n], acc[m][n], 0, 0, 0);
  }

  // C/D frag mapping: col = lane&15, row = (lane>>4)*4 + reg
  if (MODE == 0) {
#pragma unroll
    for (int m = 0; m < 4; ++m) {
      const int row = m0 + wr + m * 16 + (lane >> 4) * 4;
#pragma unroll
      for (int n = 0; n < 4; ++n) {
        const int col = n0 + wc + n * 16 + (lane & 15);
        const f32x4 v = acc[m][n];
#pragma unroll
        for (int j = 0; j < 4; ++j)
          Cb[(size_t)(row + j) * 512 + col] = f2bf(v[j]);
      }
    }
  } else {
#pragma unroll
    for (int m = 0; m < 4; ++m) {
      const int i = m0 + wr + m * 16 + (lane >> 4) * 4;
#pragma unroll
      for (int n = 0; n < 4; ++n) {
        const int d = n0 + wc + n * 16 + (lane & 15);
        const f32x4 v = acc[m][n];
        uint2 p;
        p.x = (u32)f2bf(fmaxf(v[0], 0.f)) | ((u32)f2bf(fmaxf(v[1], 0.f)) << 16);
        p.y = (u32)f2bf(fmaxf(v[2], 0.f)) | ((u32)f2bf(fmaxf(v[3], 0.f)) << 16);
        *(uint2*)&Cb[(size_t)d * 512 + i] = p;  // transposed store, i%4==0 -> 8B aligned
      }
    }
  }
}

// out[row] = mean of 512 bf16; one wave per row (row = b*512 + d)
__global__ void mean_k(const u16* __restrict__ x, float* __restrict__ out) {
  const int lane = threadIdx.x & 63;
  const int row = blockIdx.x * 4 + (threadIdx.x >> 6);
  const uint4 v = *(const uint4*)(x + (size_t)row * 512 + lane * 8);
  float s = 0.f;
  s += bf2f(v.x & 0xffffu) + bf2f(v.x >> 16);
  s += bf2f(v.y & 0xffffu) + bf2f(v.y >> 16);
  s += bf2f(v.z & 0xffffu) + bf2f(v.z >> 16);
  s += bf2f(v.w & 0xffffu) + bf2f(v.w >> 16);
#pragma unroll
  for (int o = 32; o > 0; o >>= 1) s += __shfl_down(s, o);
  if (lane == 0) out[row] = s * (1.0f / 512.0f);
}

extern "C" void kernel_launch(void* const* d_in, const int* in_sizes, int n_in,
                              void* d_out, int out_size, void* d_ws, size_t ws_size,
                              hipStream_t stream) {
  const float* enc = (const float*)d_in[0];   // (64,512,512) f32
  const float* ui  = (const float*)d_in[1];   // (5000,5000) f32
  const float* Ws  = (const float*)d_in[2];   // (2,512,512) f32
  const int*   ev  = (const int*)d_in[3];     // (64,512) int
  float* out = (float*)d_out;                 // (64,512) f32

  char* ws = (char*)d_ws;
  const size_t SLAB = (size_t)64 * 512 * 512 * 2;  // 33,554,432 B
  u16* adj = (u16*)(ws);                      // [64][512][512] bf16
  u16* tbuf = (u16*)(ws + SLAB);              // [64][512][512] bf16 row-major
  u16* xa = (u16*)(ws + 2 * SLAB);            // [64][512][512] bf16, xT layout [b][d][l]
  u16* xb = (u16*)(ws + 3 * SLAB);            // same layout
  u16* wst = (u16*)(ws + 4 * SLAB);           // [2][512][512] bf16 WsT[n][k]
  float* dg = (float*)(ws + 4 * SLAB + (size_t)2 * 512 * 512 * 2);  // [64][512] f32

  const size_t PS = (size_t)512 * 512;  // per-batch elems

  // 1) enc -> xa (transposed bf16)
  transpose_cast<<<dim3(16, 16, 64), dim3(32, 8), 0, stream>>>(enc, xa);
  // 2) Ws -> wst (transposed bf16)
  transpose_cast<<<dim3(16, 16, 2), dim3(32, 8), 0, stream>>>(Ws, wst);
  // 3) diag
  diag_k<<<128, 256, 0, stream>>>(ev, ui, dg);
  // 4) adj gather
  gather_adj<<<32768, 256, 0, stream>>>(ev, ui, dg, adj);
  // 5) layer 0: t = adj @ x  (B = xa, transposed layout)
  gemm_bt<0><<<dim3(16, 64), 256, 0, stream>>>(adj, xa, tbuf, PS, PS, PS);
  // 6) layer 0: xb^T = relu(t @ W0)
  gemm_bt<1><<<dim3(16, 64), 256, 0, stream>>>(tbuf, wst, xb, PS, 0, PS);
  // 7) layer 1: t = adj @ x
  gemm_bt<0><<<dim3(16, 64), 256, 0, stream>>>(adj, xb, tbuf, PS, PS, PS);
  // 8) layer 1: xa^T = relu(t @ W1)
  gemm_bt<1><<<dim3(16, 64), 256, 0, stream>>>(tbuf, wst + PS, xa, PS, 0, PS);
  // 9) mean over L
  mean_k<<<8192, 256, 0, stream>>>(xa, out);
}

// Round 2
// 261.045 us; speedup vs baseline: 1.0429x; 1.0429x over previous
//
#include <hip/hip_runtime.h>

typedef unsigned short u16;
typedef unsigned int u32;
typedef __bf16 bf16x8 __attribute__((ext_vector_type(8)));
typedef float f32x4 __attribute__((ext_vector_type(4)));

#define T_ 5000

__device__ __forceinline__ u16 f2bf(float f) {
  u32 u = __float_as_uint(f);
  u += 0x7fffu + ((u >> 16) & 1u);
  return (u16)(u >> 16);
}
__device__ __forceinline__ float bf2f(u32 bits16) {
  return __uint_as_float(bits16 << 16);
}

__device__ __forceinline__ void gload_lds16(const u16* g, u16* l) {
  __builtin_amdgcn_global_load_lds(
      (__attribute__((address_space(1))) void*)(u16*)g,
      (__attribute__((address_space(3))) void*)l, 16, 0, 0);
}

// dense f32 -> bf16 cast, 4 elems/thread, grid-stride
__global__ void cast_bf16(const float* __restrict__ src, u16* __restrict__ dst, int n4) {
  const int stride = gridDim.x * blockDim.x;
  for (int t = blockIdx.x * blockDim.x + threadIdx.x; t < n4; t += stride) {
    const float4 v = *(const float4*)(src + (size_t)t * 4);
    uint2 p;
    p.x = (u32)f2bf(v.x) | ((u32)f2bf(v.y) << 16);
    p.y = (u32)f2bf(v.z) | ((u32)f2bf(v.w) << 16);
    *(uint2*)(dst + (size_t)t * 4) = p;
  }
}

// f32 [Z][512][512] -> bf16 [Z][512][512] transposed: dst[z][b][a] = src[z][a][b]
__global__ void transpose_cast(const float* __restrict__ src, u16* __restrict__ dst) {
  __shared__ float tile[32][33];
  const int tx = threadIdx.x, ty = threadIdx.y;
  const int a0 = blockIdx.x * 32;
  const int b0 = blockIdx.y * 32;
  const size_t zoff = (size_t)blockIdx.z * (512 * 512);
  const float* s = src + zoff;
  u16* d = dst + zoff;
#pragma unroll
  for (int r = 0; r < 4; ++r)
    tile[ty + r * 8][tx] = s[(size_t)(a0 + ty + r * 8) * 512 + b0 + tx];
  __syncthreads();
#pragma unroll
  for (int r = 0; r < 4; ++r)
    d[(size_t)(b0 + ty + r * 8) * 512 + a0 + tx] = f2bf(tile[tx][ty + r * 8]);
}

// dg[b,j] = ui[(ev-1)*(T+1)]  (from f32 ui for accuracy)
__global__ void diag_k(const int* __restrict__ ev, const float* __restrict__ ui,
                       float* __restrict__ dg) {
  const int t = blockIdx.x * 256 + threadIdx.x;
  const long r = (long)ev[t] - 1;
  dg[t] = ui[r * (long)(T_ + 1)];
}

// adj[b][i][j] = bf16( Ub[ri*T + cj] + dg[b,j] )
// one block per (b, 8 consecutive i) -> 16 independent gathers per thread
__global__ void gather_adj2(const int* __restrict__ ev, const u16* __restrict__ Ub,
                            const float* __restrict__ dg, u16* __restrict__ adj) {
  const int blk = blockIdx.x;           // 64 groups per batch * 64 batches
  const int b = blk >> 6;
  const int i0 = (blk & 63) * 8;
  const int j = threadIdx.x * 2;
  const int base = b << 9;
  const int c0 = ev[base + j] - 1;
  const int c1 = ev[base + j + 1] - 1;
  const float d0 = dg[base + j];
  const float d1 = dg[base + j + 1];
  int ri[8];
#pragma unroll
  for (int q = 0; q < 8; ++q) ri[q] = ev[base + i0 + q] - 1;
#pragma unroll
  for (int q = 0; q < 8; ++q) {
    const u16* __restrict__ row = Ub + (size_t)ri[q] * T_;
    const float v0 = bf2f(row[c0]) + d0;
    const float v1 = bf2f(row[c1]) + d1;
    const u32 pk = (u32)f2bf(v0) | ((u32)f2bf(v1) << 16);
    *(u32*)&adj[((size_t)(base + i0 + q)) * 512 + j] = pk;
  }
}

// C = A @ B, A: [batch][512][512] bf16 row-major, Bm: [batch][512][512] bf16,
// stored TRANSPOSED (Bm[n][k] = B[k][n]).
// MODE 0: C row-major bf16.  MODE 1: C transposed (Cb[n][m]) + relu, bf16.
// 128x128 tile, BK=32, 4 waves (2x2), each wave 64x64 = 4x4 mfma_16x16x32 frags.
template <int MODE>
__global__ __launch_bounds__(256)
void gemm_bt(const u16* __restrict__ A, const u16* __restrict__ Bm,
             u16* __restrict__ C, size_t strideA, size_t strideB, size_t strideC) {
  __shared__ u16 sA[128 * 32];
  __shared__ u16 sB[128 * 32];
  const int tid = threadIdx.x;
  const int lane = tid & 63;
  const int w = tid >> 6;
  const int m0 = (blockIdx.x >> 2) * 128;
  const int n0 = (blockIdx.x & 3) * 128;
  const u16* Ab = A + (size_t)blockIdx.y * strideA;
  const u16* Bb = Bm + (size_t)blockIdx.y * strideB;
  u16* Cb = C + (size_t)blockIdx.y * strideC;
  const int wr = (w >> 1) * 64;
  const int wc = (w & 1) * 64;
  const int lr = lane & 15;
  const int lk = (lane >> 4) * 8;
  f32x4 acc[4][4] = {};

  for (int k0 = 0; k0 < 512; k0 += 32) {
    __syncthreads();
#pragma unroll
    for (int q = 0; q < 2; ++q) {
      const int cb = q * 256 + w * 64;  // wave-uniform chunk base
      const int c = cb + lane;          // this lane's chunk
      gload_lds16(Ab + (size_t)(m0 + (c >> 2)) * 512 + k0 + (c & 3) * 8, &sA[cb * 8]);
      gload_lds16(Bb + (size_t)(n0 + (c >> 2)) * 512 + k0 + (c & 3) * 8, &sB[cb * 8]);
    }
    __syncthreads();

    bf16x8 a[4], b[4];
#pragma unroll
    for (int m = 0; m < 4; ++m)
      a[m] = *(const bf16x8*)&sA[(wr + m * 16 + lr) * 32 + lk];
#pragma unroll
    for (int n = 0; n < 4; ++n)
      b[n] = *(const bf16x8*)&sB[(wc + n * 16 + lr) * 32 + lk];
#pragma unroll
    for (int m = 0; m < 4; ++m)
#pragma unroll
      for (int n = 0; n < 4; ++n)
        acc[m][n] = __builtin_amdgcn_mfma_f32_16x16x32_bf16(a[m], b[n], acc[m][n], 0, 0, 0);
  }

  // C/D frag mapping: col = lane&15, row = (lane>>4)*4 + reg
  if (MODE == 0) {
#pragma unroll
    for (int m = 0; m < 4; ++m) {
      const int row = m0 + wr + m * 16 + (lane >> 4) * 4;
#pragma unroll
      for (int n = 0; n < 4; ++n) {
        const int col = n0 + wc + n * 16 + (lane & 15);
        const f32x4 v = acc[m][n];
#pragma unroll
        for (int j = 0; j < 4; ++j)
          Cb[(size_t)(row + j) * 512 + col] = f2bf(v[j]);
      }
    }
  } else {
#pragma unroll
    for (int m = 0; m < 4; ++m) {
      const int i = m0 + wr + m * 16 + (lane >> 4) * 4;
#pragma unroll
      for (int n = 0; n < 4; ++n) {
        const int d = n0 + wc + n * 16 + (lane & 15);
        const f32x4 v = acc[m][n];
        uint2 p;
        p.x = (u32)f2bf(fmaxf(v[0], 0.f)) | ((u32)f2bf(fmaxf(v[1], 0.f)) << 16);
        p.y = (u32)f2bf(fmaxf(v[2], 0.f)) | ((u32)f2bf(fmaxf(v[3], 0.f)) << 16);
        *(uint2*)&Cb[(size_t)d * 512 + i] = p;  // transposed store
      }
    }
  }
}

// out[row] = mean of 512 bf16; one wave per row (row = b*512 + d)
__global__ void mean_k(const u16* __restrict__ x, float* __restrict__ out) {
  const int lane = threadIdx.x & 63;
  const int row = blockIdx.x * 4 + (threadIdx.x >> 6);
  const uint4 v = *(const uint4*)(x + (size_t)row * 512 + lane * 8);
  float s = 0.f;
  s += bf2f(v.x & 0xffffu) + bf2f(v.x >> 16);
  s += bf2f(v.y & 0xffffu) + bf2f(v.y >> 16);
  s += bf2f(v.z & 0xffffu) + bf2f(v.z >> 16);
  s += bf2f(v.w & 0xffffu) + bf2f(v.w >> 16);
#pragma unroll
  for (int o = 32; o > 0; o >>= 1) s += __shfl_down(s, o);
  if (lane == 0) out[row] = s * (1.0f / 512.0f);
}

extern "C" void kernel_launch(void* const* d_in, const int* in_sizes, int n_in,
                              void* d_out, int out_size, void* d_ws, size_t ws_size,
                              hipStream_t stream) {
  const float* enc = (const float*)d_in[0];   // (64,512,512) f32
  const float* ui  = (const float*)d_in[1];   // (5000,5000) f32
  const float* Ws  = (const float*)d_in[2];   // (2,512,512) f32
  const int*   ev  = (const int*)d_in[3];     // (64,512) int
  float* out = (float*)d_out;                 // (64,512) f32

  char* ws = (char*)d_ws;
  const size_t SLAB = (size_t)64 * 512 * 512 * 2;  // 33,554,432 B
  // slab layout (note order: tbuf & xb adjacent so Ub can alias both):
  u16* adj  = (u16*)(ws);                     // [0,S): adj bf16
  u16* tbuf = (u16*)(ws + SLAB);              // [S,2S): intermediate t
  u16* xb   = (u16*)(ws + 2 * SLAB);          // [2S,3S): x after layer 0 (xT layout)
  u16* xa   = (u16*)(ws + 3 * SLAB);          // [3S,4S): encT, then final xT
  u16* wst  = (u16*)(ws + 4 * SLAB);          // [2][512][512] WsT[n][k]
  float* dg = (float*)(ws + 4 * SLAB + (size_t)2 * 512 * 512 * 2);  // [64][512]
  // Ub (bf16 ui, 50 MB) aliases tbuf+xb — both dead until GEMM5/6, Ub dead after gather
  u16* Ub   = (u16*)(ws + SLAB);

  const size_t PS = (size_t)512 * 512;  // per-batch elems

  // 1) ui -> Ub (bf16, dense)
  cast_bf16<<<2048, 256, 0, stream>>>(ui, Ub, (T_ * T_) / 4);
  // 2) enc -> xa (transposed bf16)
  transpose_cast<<<dim3(16, 16, 64), dim3(32, 8), 0, stream>>>(enc, xa);
  // 3) Ws -> wst (transposed bf16)
  transpose_cast<<<dim3(16, 16, 2), dim3(32, 8), 0, stream>>>(Ws, wst);
  // 4) diag (from f32 ui)
  diag_k<<<128, 256, 0, stream>>>(ev, ui, dg);
  // 5) adj gather from bf16 Ub, 8 rows per block
  gather_adj2<<<4096, 256, 0, stream>>>(ev, Ub, dg, adj);
  // 6) layer 0: t = adj @ x   (overwrites Ub head — Ub dead now)
  gemm_bt<0><<<dim3(16, 64), 256, 0, stream>>>(adj, xa, tbuf, PS, PS, PS);
  // 7) layer 0: xb^T = relu(t @ W0)  (overwrites Ub tail)
  gemm_bt<1><<<dim3(16, 64), 256, 0, stream>>>(tbuf, wst, xb, PS, 0, PS);
  // 8) layer 1: t = adj @ x
  gemm_bt<0><<<dim3(16, 64), 256, 0, stream>>>(adj, xb, tbuf, PS, PS, PS);
  // 9) layer 1: xa^T = relu(t @ W1)
  gemm_bt<1><<<dim3(16, 64), 256, 0, stream>>>(tbuf, wst + PS, xa, PS, 0, PS);
  // 10) mean over L
  mean_k<<<8192, 256, 0, stream>>>(xa, out);
}

// Round 3
// 212.365 us; speedup vs baseline: 1.2819x; 1.2292x over previous
//
#include <hip/hip_runtime.h>

typedef unsigned short u16;
typedef unsigned int u32;
typedef __bf16 bf16x8 __attribute__((ext_vector_type(8)));
typedef float f32x4 __attribute__((ext_vector_type(4)));

#define T_ 5000
#define CAP 96  // max instances per distinct row served by grow_gather (P(overflow)~e-80; ovf kernel guarantees correctness)

__device__ __forceinline__ u16 f2bf(float f) {
  u32 u = __float_as_uint(f);
  u += 0x7fffu + ((u >> 16) & 1u);
  return (u16)(u >> 16);
}
__device__ __forceinline__ float bf2f(u32 bits16) {
  return __uint_as_float(bits16 << 16);
}

__device__ __forceinline__ void gload_lds16(const u16* g, u16* l) {
  __builtin_amdgcn_global_load_lds(
      (__attribute__((address_space(1))) void*)(u16*)g,
      (__attribute__((address_space(3))) void*)l, 16, 0, 0);
}

// f32 [Z][512][512] -> bf16 [Z][512][512] transposed: dst[z][b][a] = src[z][a][b]
__global__ void transpose_cast(const float* __restrict__ src, u16* __restrict__ dst) {
  __shared__ float tile[32][33];
  const int tx = threadIdx.x, ty = threadIdx.y;
  const int a0 = blockIdx.x * 32;
  const int b0 = blockIdx.y * 32;
  const size_t zoff = (size_t)blockIdx.z * (512 * 512);
  const float* s = src + zoff;
  u16* d = dst + zoff;
#pragma unroll
  for (int r = 0; r < 4; ++r)
    tile[ty + r * 8][tx] = s[(size_t)(a0 + ty + r * 8) * 512 + b0 + tx];
  __syncthreads();
#pragma unroll
  for (int r = 0; r < 4; ++r)
    d[(size_t)(b0 + ty + r * 8) * 512 + a0 + tx] = f2bf(tile[tx][ty + r * 8]);
}

// zero the bucket counters (cnt[5000]) + overflow counter (cnt[5000])
__global__ void zero_k(int* __restrict__ cnt) {
  const int t = blockIdx.x * 256 + threadIdx.x;
  if (t < 5001) cnt[t] = 0;
}

// cd[t] = {col = ev[t]-1, bits(diag = ui[col*5001])}; also bucket-fill: instance t into list[row]
__global__ void fill_k(const int* __restrict__ ev, const float* __restrict__ ui,
                       int2* __restrict__ cd, int* __restrict__ cnt,
                       int* __restrict__ list, int* __restrict__ ovf) {
  const int t = blockIdx.x * 256 + threadIdx.x;  // 0..32767 (= b*512 + i)
  const int r = ev[t] - 1;
  int2 v;
  v.x = r;
  v.y = __float_as_int(ui[(size_t)r * (T_ + 1)]);
  cd[t] = v;
  const int pos = atomicAdd(&cnt[r], 1);
  if (pos < CAP) list[r * CAP + pos] = t;
  else { const int o = atomicAdd(&cnt[5000], 1); ovf[o] = t; }
}

// one block per distinct ui row: stage row in LDS (dense), serve all instances
__global__ __launch_bounds__(256)
void grow_gather(const float* __restrict__ ui, const int2* __restrict__ cd,
                 const int* __restrict__ cnt, const int* __restrict__ list,
                 u16* __restrict__ adj) {
  const int r = blockIdx.x;
  int c = cnt[r];
  if (c <= 0) return;
  if (c > CAP) c = CAP;
  __shared__ float row[5000];
  const float* __restrict__ src = ui + (size_t)r * T_;
  for (int t = threadIdx.x; t < 1250; t += 256)
    *(float4*)&row[t * 4] = *(const float4*)&src[t * 4];
  __syncthreads();
  const int j = threadIdx.x * 2;
  for (int q = 0; q < c; ++q) {
    const int t = list[r * CAP + q];
    const int base = (t >> 9) << 9;  // b*512
    const int4 p = *(const int4*)&cd[base + j];  // {c0, dg0bits, c1, dg1bits}
    const float v0 = row[p.x] + __int_as_float(p.y);
    const float v1 = row[p.z] + __int_as_float(p.w);
    const u32 pk = (u32)f2bf(v0) | ((u32)f2bf(v1) << 16);
    *(u32*)&adj[(size_t)t * 512 + j] = pk;
  }
}

// correctness fallback for bucket overflow (expected 0 instances)
__global__ void ovf_gather(const float* __restrict__ ui, const int2* __restrict__ cd,
                           const int* __restrict__ cnt, const int* __restrict__ ovf,
                           u16* __restrict__ adj) {
  const int n = cnt[5000];
  for (int q = blockIdx.x; q < n; q += gridDim.x) {
    const int t = ovf[q];
    const int base = (t >> 9) << 9;
    const long r = (long)cd[t].x;
    const float* __restrict__ row = ui + r * (long)T_;
    const int j = threadIdx.x * 2;
    const int4 p = *(const int4*)&cd[base + j];
    const u32 pk = (u32)f2bf(row[p.x] + __int_as_float(p.y)) |
                   ((u32)f2bf(row[p.z] + __int_as_float(p.w)) << 16);
    *(u32*)&adj[(size_t)t * 512 + j] = pk;
  }
}

// C = A @ B, A row-major bf16, Bm transposed (Bm[n][k] = B[k][n]).
// MODE 0: C row-major bf16.
// MODE 1: C transposed (Cb[n][m]) + relu, bf16.
// MODE 2: relu + column-sum partials -> P[b][slot][d] (no C store; mean fusion).
// 128x128 tile, BK=32, 4 waves (2x2), each wave 64x64 = 4x4 mfma_16x16x32 frags.
template <int MODE>
__global__ __launch_bounds__(256)
void gemm_bt(const u16* __restrict__ A, const u16* __restrict__ Bm,
             u16* __restrict__ C, size_t strideA, size_t strideB, size_t strideC,
             float* __restrict__ P) {
  __shared__ u16 sA[128 * 32];
  __shared__ u16 sB[128 * 32];
  const int tid = threadIdx.x;
  const int lane = tid & 63;
  const int w = tid >> 6;
  const int m0 = (blockIdx.x >> 2) * 128;
  const int n0 = (blockIdx.x & 3) * 128;
  const u16* Ab = A + (size_t)blockIdx.y * strideA;
  const u16* Bb = Bm + (size_t)blockIdx.y * strideB;
  u16* Cb = C + (size_t)blockIdx.y * strideC;
  const int wr = (w >> 1) * 64;
  const int wc = (w & 1) * 64;
  const int lr = lane & 15;
  const int lk = (lane >> 4) * 8;
  f32x4 acc[4][4] = {};

  for (int k0 = 0; k0 < 512; k0 += 32) {
    __syncthreads();
#pragma unroll
    for (int q = 0; q < 2; ++q) {
      const int cb = q * 256 + w * 64;  // wave-uniform chunk base
      const int c = cb + lane;          // this lane's chunk
      gload_lds16(Ab + (size_t)(m0 + (c >> 2)) * 512 + k0 + (c & 3) * 8, &sA[cb * 8]);
      gload_lds16(Bb + (size_t)(n0 + (c >> 2)) * 512 + k0 + (c & 3) * 8, &sB[cb * 8]);
    }
    __syncthreads();

    bf16x8 a[4], b[4];
#pragma unroll
    for (int m = 0; m < 4; ++m)
      a[m] = *(const bf16x8*)&sA[(wr + m * 16 + lr) * 32 + lk];
#pragma unroll
    for (int n = 0; n < 4; ++n)
      b[n] = *(const bf16x8*)&sB[(wc + n * 16 + lr) * 32 + lk];
#pragma unroll
    for (int m = 0; m < 4; ++m)
#pragma unroll
      for (int n = 0; n < 4; ++n)
        acc[m][n] = __builtin_amdgcn_mfma_f32_16x16x32_bf16(a[m], b[n], acc[m][n], 0, 0, 0);
  }

  // C/D frag mapping: col = lane&15, row = (lane>>4)*4 + reg
  if (MODE == 0) {
#pragma unroll
    for (int m = 0; m < 4; ++m) {
      const int row = m0 + wr + m * 16 + (lane >> 4) * 4;
#pragma unroll
      for (int n = 0; n < 4; ++n) {
        const int col = n0 + wc + n * 16 + (lane & 15);
        const f32x4 v = acc[m][n];
#pragma unroll
        for (int j = 0; j < 4; ++j)
          Cb[(size_t)(row + j) * 512 + col] = f2bf(v[j]);
      }
    }
  } else if (MODE == 1) {
#pragma unroll
    for (int m = 0; m < 4; ++m) {
      const int i = m0 + wr + m * 16 + (lane >> 4) * 4;
#pragma unroll
      for (int n = 0; n < 4; ++n) {
        const int d = n0 + wc + n * 16 + (lane & 15);
        const f32x4 v = acc[m][n];
        uint2 p;
        p.x = (u32)f2bf(fmaxf(v[0], 0.f)) | ((u32)f2bf(fmaxf(v[1], 0.f)) << 16);
        p.y = (u32)f2bf(fmaxf(v[2], 0.f)) | ((u32)f2bf(fmaxf(v[3], 0.f)) << 16);
        *(uint2*)&Cb[(size_t)d * 512 + i] = p;  // transposed store
      }
    }
  } else {
    // mean fusion: per output col d, sum relu(v) over this wave's 64 m-rows,
    // reduce the 4 row-groups (lane>>4) via shfl_xor, store one partial.
    const int slot = (blockIdx.x >> 2) * 2 + (w >> 1);  // m-tile * 2 + wave-row
#pragma unroll
    for (int n = 0; n < 4; ++n) {
      float s = 0.f;
#pragma unroll
      for (int m = 0; m < 4; ++m) {
        const f32x4 v = acc[m][n];
#pragma unroll
        for (int j = 0; j < 4; ++j) s += fmaxf(v[j], 0.f);
      }
      s += __shfl_xor(s, 16);
      s += __shfl_xor(s, 32);
      if ((lane >> 4) == 0) {
        const int d = n0 + wc + n * 16 + lane;
        P[((size_t)blockIdx.y * 8 + slot) * 512 + d] = s;
      }
    }
  }
}

// out[b,d] = (1/512) * sum_slot P[b][slot][d]
__global__ void reduce_mean(const float* __restrict__ P, float* __restrict__ out) {
  const int t = blockIdx.x * 256 + threadIdx.x;  // 0..32767
  const int b = t >> 9, d = t & 511;
  float s = 0.f;
#pragma unroll
  for (int q = 0; q < 8; ++q) s += P[((size_t)b * 8 + q) * 512 + d];
  out[t] = s * (1.0f / 512.0f);
}

extern "C" void kernel_launch(void* const* d_in, const int* in_sizes, int n_in,
                              void* d_out, int out_size, void* d_ws, size_t ws_size,
                              hipStream_t stream) {
  const float* enc = (const float*)d_in[0];   // (64,512,512) f32
  const float* ui  = (const float*)d_in[1];   // (5000,5000) f32
  const float* Ws  = (const float*)d_in[2];   // (2,512,512) f32
  const int*   ev  = (const int*)d_in[3];     // (64,512) int
  float* out = (float*)d_out;                 // (64,512) f32

  char* ws = (char*)d_ws;
  const size_t SLAB = (size_t)64 * 512 * 512 * 2;  // 33,554,432 B
  u16* adj  = (u16*)(ws);                      // [0,S)
  u16* tbuf = (u16*)(ws + SLAB);               // [S,2S)
  u16* xb   = (u16*)(ws + 2 * SLAB);           // [2S,3S)
  u16* xa   = (u16*)(ws + 3 * SLAB);           // [3S,4S): enc^T bf16
  char* p = ws + 4 * SLAB;
  u16* wst  = (u16*)p;  p += (size_t)2 * 512 * 512 * 2;   // 1 MB
  int2* cd  = (int2*)p; p += (size_t)32768 * 8;           // 256 KB
  int* cnt  = (int*)p;  p += 5008 * 4;                    // counters (+ovf at [5000])
  int* list = (int*)p;  p += (size_t)5000 * CAP * 4;      // 1.92 MB
  int* ovf  = (int*)p;  p += (size_t)32768 * 4;           // 128 KB
  float* P  = (float*)p;                                  // [64][8][512] f32, 1 MB

  const size_t PS = (size_t)512 * 512;  // per-batch elems

  // bucket instances by ui-row + build (col, diag) table
  zero_k<<<20, 256, 0, stream>>>(cnt);
  fill_k<<<128, 256, 0, stream>>>(ev, ui, cd, cnt, list, ovf);
  // enc -> xa (transposed bf16); Ws -> wst
  transpose_cast<<<dim3(16, 16, 64), dim3(32, 8), 0, stream>>>(enc, xa);
  transpose_cast<<<dim3(16, 16, 2), dim3(32, 8), 0, stream>>>(Ws, wst);
  // dedup gather: one block per distinct ui row
  grow_gather<<<5000, 256, 0, stream>>>(ui, cd, cnt, list, adj);
  ovf_gather<<<8, 256, 0, stream>>>(ui, cd, cnt, ovf, adj);
  // layer 0
  gemm_bt<0><<<dim3(16, 64), 256, 0, stream>>>(adj, xa, tbuf, PS, PS, PS, nullptr);
  gemm_bt<1><<<dim3(16, 64), 256, 0, stream>>>(tbuf, wst, xb, PS, 0, PS, nullptr);
  // layer 1 (+ fused mean partials)
  gemm_bt<0><<<dim3(16, 64), 256, 0, stream>>>(adj, xb, tbuf, PS, PS, PS, nullptr);
  gemm_bt<2><<<dim3(16, 64), 256, 0, stream>>>(tbuf, wst + PS, nullptr, PS, 0, 0, P);
  // finish mean
  reduce_mean<<<128, 256, 0, stream>>>(P, out);
}

// Round 4
// 155.744 us; speedup vs baseline: 1.7479x; 1.3635x over previous
//
#include <hip/hip_runtime.h>

typedef unsigned short u16;
typedef unsigned int u32;
typedef __bf16 bf16x8 __attribute__((ext_vector_type(8)));
typedef float f32x4 __attribute__((ext_vector_type(4)));
typedef int i32x4 __attribute__((ext_vector_type(4)));

#define T_ 5000
#define CAP 96  // bucket capacity; ovf kernel guarantees correctness on overflow

__device__ __forceinline__ u16 f2bf(float f) {
  u32 u = __float_as_uint(f);
  u += 0x7fffu + ((u >> 16) & 1u);
  return (u16)(u >> 16);
}
__device__ __forceinline__ float bf2f(u32 bits16) {
  return __uint_as_float(bits16 << 16);
}

__device__ __forceinline__ void gload_lds16(const u16* g, u16* l) {
  __builtin_amdgcn_global_load_lds(
      (__attribute__((address_space(1))) void*)(u16*)g,
      (__attribute__((address_space(3))) void*)l, 16, 0, 0);
}

__device__ __forceinline__ u32 lds_off(const void* p) {
  return (u32)(uintptr_t)(__attribute__((address_space(3))) const void*)p;
}

// f32 [Z][512][512] -> bf16 [Z][512][512] transposed: dst[z][b][a] = src[z][a][b]
__global__ void transpose_cast(const float* __restrict__ src, u16* __restrict__ dst) {
  __shared__ float tile[32][33];
  const int tx = threadIdx.x, ty = threadIdx.y;
  const int a0 = blockIdx.x * 32;
  const int b0 = blockIdx.y * 32;
  const size_t zoff = (size_t)blockIdx.z * (512 * 512);
  const float* s = src + zoff;
  u16* d = dst + zoff;
#pragma unroll
  for (int r = 0; r < 4; ++r)
    tile[ty + r * 8][tx] = s[(size_t)(a0 + ty + r * 8) * 512 + b0 + tx];
  __syncthreads();
#pragma unroll
  for (int r = 0; r < 4; ++r)
    d[(size_t)(b0 + ty + r * 8) * 512 + a0 + tx] = f2bf(tile[tx][ty + r * 8]);
}

__global__ void zero_k(int* __restrict__ cnt) {
  const int t = blockIdx.x * 256 + threadIdx.x;
  if (t < 5001) cnt[t] = 0;
}

// cd[t] = {col, bits(diag)}; bucket instance t into list[row]
__global__ void fill_k(const int* __restrict__ ev, const float* __restrict__ ui,
                       int2* __restrict__ cd, int* __restrict__ cnt,
                       int* __restrict__ list, int* __restrict__ ovf) {
  const int t = blockIdx.x * 256 + threadIdx.x;  // 0..32767
  const int r = ev[t] - 1;
  int2 v;
  v.x = r;
  v.y = __float_as_int(ui[(size_t)r * (T_ + 1)]);
  cd[t] = v;
  const int pos = atomicAdd(&cnt[r], 1);
  if (pos < CAP) list[r * CAP + pos] = t;
  else { const int o = atomicAdd(&cnt[5000], 1); ovf[o] = t; }
}

// one block per distinct ui row: stage row in LDS, serve all its instances
__global__ __launch_bounds__(256)
void grow_gather(const float* __restrict__ ui, const int2* __restrict__ cd,
                 const int* __restrict__ cnt, const int* __restrict__ list,
                 u16* __restrict__ adj) {
  const int r = blockIdx.x;
  int c = cnt[r];
  if (c <= 0) return;
  if (c > CAP) c = CAP;
  __shared__ float row[5000];
  const float* __restrict__ src = ui + (size_t)r * T_;
  for (int t = threadIdx.x; t < 1250; t += 256)
    *(float4*)&row[t * 4] = *(const float4*)&src[t * 4];
  __syncthreads();
  const int j = threadIdx.x * 2;
  for (int q = 0; q < c; ++q) {
    const int t = list[r * CAP + q];
    const int base = (t >> 9) << 9;
    const int4 p = *(const int4*)&cd[base + j];
    const float v0 = row[p.x] + __int_as_float(p.y);
    const float v1 = row[p.z] + __int_as_float(p.w);
    const u32 pk = (u32)f2bf(v0) | ((u32)f2bf(v1) << 16);
    *(u32*)&adj[(size_t)t * 512 + j] = pk;
  }
}

__global__ void ovf_gather(const float* __restrict__ ui, const int2* __restrict__ cd,
                           const int* __restrict__ cnt, const int* __restrict__ ovf,
                           u16* __restrict__ adj) {
  const int n = cnt[5000];
  for (int q = blockIdx.x; q < n; q += gridDim.x) {
    const int t = ovf[q];
    const int base = (t >> 9) << 9;
    const long r = (long)cd[t].x;
    const float* __restrict__ row = ui + r * (long)T_;
    const int j = threadIdx.x * 2;
    const int4 p = *(const int4*)&cd[base + j];
    const u32 pk = (u32)f2bf(row[p.x] + __int_as_float(p.y)) |
                   ((u32)f2bf(row[p.z] + __int_as_float(p.w)) << 16);
    *(u32*)&adj[(size_t)t * 512 + j] = pk;
  }
}

// ---------------------------------------------------------------------------
// 256x256-tile GEMM, BK=32, 8 waves (2Mx4N), wave tile 128x64.
// 4 LDS buffers, prefetch distance 3, counted vmcnt(8), raw barriers,
// inline-asm ds_read_b128, row-XOR LDS swizzle via pre-swizzled global src,
// chunked XCD swizzle on blockIdx. A row-major [m][k], Bm n-major [n][k].
// MODE 0: C row-major bf16. MODE 1: C transposed + relu. MODE 2: relu+col-sum
// partials P[b][slot][d], slot = tm*2+wm (4 slots).
// LDS swizzle (both sides, involution): tile byte (row, kb) lives at LDS byte
//   (row>>1)*128 + ((((row&1)<<6)|kb) ^ (((row>>1)&7)<<4)).
// ---------------------------------------------------------------------------
template <int MODE>
__global__ __launch_bounds__(512, 2)
void gemm256(const u16* __restrict__ A, const u16* __restrict__ Bm,
             u16* __restrict__ C, size_t strideA, size_t strideB, size_t strideC,
             float* __restrict__ P) {
  extern __shared__ u16 smem[];  // A: 4 bufs x 16KB @ [0,64K); B: 4 x 16KB @ [64K,128K)
  const int tid = threadIdx.x;
  const int lane = tid & 63;
  const int w = tid >> 6;
  const int wm = w >> 2, wn = w & 3;
  // chunked XCD swizzle (gridDim.x % 8 == 0): consecutive mapped ids -> same XCD
  const int chunk = gridDim.x >> 3;
  const int wg = blockIdx.x;
  const int mapped = (wg & 7) * chunk + (wg >> 3);
  const int batch = mapped >> 2;
  const int tm = (mapped >> 1) & 1, tn = mapped & 1;
  const int m0 = tm << 8, n0 = tn << 8;
  const u16* __restrict__ Ab = A + (size_t)batch * strideA;
  const u16* __restrict__ Bb = Bm + (size_t)batch * strideB;

  // staging: chunk c = r*512+tid (16B each); inverse-swizzle to tile coords
  const u16* gA[2];
  const u16* gB[2];
  u32 ldA[2], ldB[2];
#pragma unroll
  for (int r = 0; r < 2; ++r) {
    const int c = r * 512 + tid;
    const int L = c * 16;
    const int p = L >> 7;
    const int off = (L & 127) ^ ((p & 7) << 4);
    const int m = p * 2 + (off >> 6);
    const int kb = off & 63;
    gA[r] = Ab + (size_t)(m0 + m) * 512 + (kb >> 1);
    gB[r] = Bb + (size_t)(n0 + m) * 512 + (kb >> 1);
    ldA[r] = (u32)((r * 512 + w * 64) * 8);            // u16 elems, + lane*16B by HW
    ldB[r] = (u32)(32768 + (r * 512 + w * 64) * 8);
  }

  // frag LDS byte offsets (k-tile-invariant)
  const int lr = lane & 15;
  const int kb = (lane >> 4) << 4;
  u32 aOff[8], bOff[4];
#pragma unroll
  for (int m = 0; m < 8; ++m) {
    const int row = wm * 128 + m * 16 + lr;
    aOff[m] = (u32)((row >> 1) * 128 + ((((row & 1) << 6) | kb) ^ (((row >> 1) & 7) << 4)));
  }
#pragma unroll
  for (int n = 0; n < 4; ++n) {
    const int row = wn * 64 + n * 16 + lr;
    bOff[n] = (u32)(65536 + (row >> 1) * 128 + ((((row & 1) << 6) | kb) ^ (((row >> 1) & 7) << 4)));
  }
  const u32 ldsBase = lds_off(smem);

  f32x4 acc[8][4] = {};

  auto stage = [&](int t) {
    const u32 bo = (u32)(t & 3) * 8192;  // elems per buf (16 KB)
#pragma unroll
    for (int r = 0; r < 2; ++r) {
      gload_lds16(gA[r] + t * 32, smem + bo + ldA[r]);
      gload_lds16(gB[r] + t * 32, smem + bo + ldB[r]);
    }
  };

  stage(0); stage(1); stage(2);

#pragma unroll
  for (int t = 0; t < 16; ++t) {
    // tile t's 4 loads are older than the (<=8) loads of tiles t+1,t+2
    if (t <= 13)      asm volatile("s_waitcnt vmcnt(8)" ::: "memory");
    else if (t == 14) asm volatile("s_waitcnt vmcnt(4)" ::: "memory");
    else              asm volatile("s_waitcnt vmcnt(0)" ::: "memory");
    __builtin_amdgcn_sched_barrier(0);
    if (t + 3 < 16) stage(t + 3);  // overwrites buf[(t-1)&3]; guarded by prev B2
    asm volatile("" ::: "memory");
    __builtin_amdgcn_s_barrier();  // B1: every wave's tile-t loads have landed
    asm volatile("" ::: "memory");

    const u32 base = ldsBase + (u32)(t & 3) * 16384;
    i32x4 araw[8], braw[4];
#pragma unroll
    for (int m = 0; m < 8; ++m)
      asm volatile("ds_read_b128 %0, %1" : "=v"(araw[m]) : "v"(base + aOff[m]));
#pragma unroll
    for (int n = 0; n < 4; ++n)
      asm volatile("ds_read_b128 %0, %1" : "=v"(braw[n]) : "v"(base + bOff[n]));
    asm volatile("s_waitcnt lgkmcnt(0)" ::: "memory");
    __builtin_amdgcn_sched_barrier(0);  // rule 18: pin MFMA after the wait

    __builtin_amdgcn_s_setprio(1);
#pragma unroll
    for (int m = 0; m < 8; ++m)
#pragma unroll
      for (int n = 0; n < 4; ++n)
        acc[m][n] = __builtin_amdgcn_mfma_f32_16x16x32_bf16(
            __builtin_bit_cast(bf16x8, araw[m]),
            __builtin_bit_cast(bf16x8, braw[n]), acc[m][n], 0, 0, 0);
    __builtin_amdgcn_s_setprio(0);
    asm volatile("" ::: "memory");
    __builtin_amdgcn_s_barrier();  // B2: all reads of buf[t&3] done before reuse
    __builtin_amdgcn_sched_barrier(0);
  }

  u16* Cb = C + (size_t)batch * strideC;
  // C/D frag mapping: col = lane&15, row = (lane>>4)*4 + j
  if (MODE == 0) {
#pragma unroll
    for (int m = 0; m < 8; ++m) {
      const int row = m0 + wm * 128 + m * 16 + (lane >> 4) * 4;
#pragma unroll
      for (int n = 0; n < 4; ++n) {
        const int col = n0 + wn * 64 + n * 16 + (lane & 15);
        const f32x4 v = acc[m][n];
#pragma unroll
        for (int j = 0; j < 4; ++j)
          Cb[(size_t)(row + j) * 512 + col] = f2bf(v[j]);
      }
    }
  } else if (MODE == 1) {
#pragma unroll
    for (int m = 0; m < 8; ++m) {
      const int i = m0 + wm * 128 + m * 16 + (lane >> 4) * 4;
#pragma unroll
      for (int n = 0; n < 4; ++n) {
        const int d = n0 + wn * 64 + n * 16 + (lane & 15);
        const f32x4 v = acc[m][n];
        uint2 p;
        p.x = (u32)f2bf(fmaxf(v[0], 0.f)) | ((u32)f2bf(fmaxf(v[1], 0.f)) << 16);
        p.y = (u32)f2bf(fmaxf(v[2], 0.f)) | ((u32)f2bf(fmaxf(v[3], 0.f)) << 16);
        *(uint2*)&Cb[(size_t)d * 512 + i] = p;  // transposed store
      }
    }
  } else {
    const int slot = tm * 2 + wm;  // 4 partial slots over the 256 m-rows x 2 tiles
#pragma unroll
    for (int n = 0; n < 4; ++n) {
      float s = 0.f;
#pragma unroll
      for (int m = 0; m < 8; ++m) {
        const f32x4 v = acc[m][n];
#pragma unroll
        for (int j = 0; j < 4; ++j) s += fmaxf(v[j], 0.f);
      }
      s += __shfl_xor(s, 16);
      s += __shfl_xor(s, 32);
      if ((lane >> 4) == 0) {
        const int d = n0 + wn * 64 + n * 16 + lane;
        P[((size_t)batch * 4 + slot) * 512 + d] = s;
      }
    }
  }
}

// out[b,d] = (1/512) * sum_slot P[b][slot][d]
__global__ void reduce_mean(const float* __restrict__ P, float* __restrict__ out) {
  const int t = blockIdx.x * 256 + threadIdx.x;  // 0..32767
  const int b = t >> 9, d = t & 511;
  float s = 0.f;
#pragma unroll
  for (int q = 0; q < 4; ++q) s += P[((size_t)b * 4 + q) * 512 + d];
  out[t] = s * (1.0f / 512.0f);
}

extern "C" void kernel_launch(void* const* d_in, const int* in_sizes, int n_in,
                              void* d_out, int out_size, void* d_ws, size_t ws_size,
                              hipStream_t stream) {
  const float* enc = (const float*)d_in[0];   // (64,512,512) f32
  const float* ui  = (const float*)d_in[1];   // (5000,5000) f32
  const float* Ws  = (const float*)d_in[2];   // (2,512,512) f32
  const int*   ev  = (const int*)d_in[3];     // (64,512) int
  float* out = (float*)d_out;                 // (64,512) f32

  char* ws = (char*)d_ws;
  const size_t SLAB = (size_t)64 * 512 * 512 * 2;  // 32 MiB
  u16* adj  = (u16*)(ws);
  u16* tbuf = (u16*)(ws + SLAB);
  u16* xb   = (u16*)(ws + 2 * SLAB);
  u16* xa   = (u16*)(ws + 3 * SLAB);
  char* p = ws + 4 * SLAB;
  u16* wst  = (u16*)p;  p += (size_t)2 * 512 * 512 * 2;
  int2* cd  = (int2*)p; p += (size_t)32768 * 8;
  int* cnt  = (int*)p;  p += 5008 * 4;
  int* list = (int*)p;  p += (size_t)5000 * CAP * 4;
  int* ovf  = (int*)p;  p += (size_t)32768 * 4;
  float* P  = (float*)p;                               // [64][4][512] f32

  const size_t PS = (size_t)512 * 512;
  const size_t SMEM = 131072;
  (void)hipFuncSetAttribute(reinterpret_cast<const void*>(gemm256<0>),
                            hipFuncAttributeMaxDynamicSharedMemorySize, (int)SMEM);
  (void)hipFuncSetAttribute(reinterpret_cast<const void*>(gemm256<1>),
                            hipFuncAttributeMaxDynamicSharedMemorySize, (int)SMEM);
  (void)hipFuncSetAttribute(reinterpret_cast<const void*>(gemm256<2>),
                            hipFuncAttributeMaxDynamicSharedMemorySize, (int)SMEM);

  zero_k<<<20, 256, 0, stream>>>(cnt);
  fill_k<<<128, 256, 0, stream>>>(ev, ui, cd, cnt, list, ovf);
  transpose_cast<<<dim3(16, 16, 64), dim3(32, 8), 0, stream>>>(enc, xa);
  transpose_cast<<<dim3(16, 16, 2), dim3(32, 8), 0, stream>>>(Ws, wst);
  grow_gather<<<5000, 256, 0, stream>>>(ui, cd, cnt, list, adj);
  ovf_gather<<<8, 256, 0, stream>>>(ui, cd, cnt, ovf, adj);
  // layer 0
  gemm256<0><<<256, 512, SMEM, stream>>>(adj, xa, tbuf, PS, PS, PS, nullptr);
  gemm256<1><<<256, 512, SMEM, stream>>>(tbuf, wst, xb, PS, 0, PS, nullptr);
  // layer 1 (+ fused mean partials)
  gemm256<0><<<256, 512, SMEM, stream>>>(adj, xb, tbuf, PS, PS, PS, nullptr);
  gemm256<2><<<256, 512, SMEM, stream>>>(tbuf, wst + PS, nullptr, PS, 0, 0, P);
  reduce_mean<<<128, 256, 0, stream>>>(P, out);
}

// Round 5
// 141.835 us; speedup vs baseline: 1.9194x; 1.0981x over previous
//
#include <hip/hip_runtime.h>

typedef unsigned short u16;
typedef unsigned int u32;
typedef __bf16 bf16x8 __attribute__((ext_vector_type(8)));
typedef float f32x4 __attribute__((ext_vector_type(4)));
typedef int i32x4 __attribute__((ext_vector_type(4)));
typedef u32 u32x2 __attribute__((ext_vector_type(2)));
typedef u32 u32x4 __attribute__((ext_vector_type(4)));

#define T_ 5000
#define CAP 96  // bucket capacity; ovf kernel guarantees correctness on overflow

__device__ __forceinline__ u16 f2bf(float f) {
  u32 u = __float_as_uint(f);
  u += 0x7fffu + ((u >> 16) & 1u);
  return (u16)(u >> 16);
}
__device__ __forceinline__ float bf2f(u32 bits16) {
  return __uint_as_float(bits16 << 16);
}

__device__ __forceinline__ void gload_lds16(const u16* g, u16* l) {
  __builtin_amdgcn_global_load_lds(
      (__attribute__((address_space(1))) void*)(u16*)g,
      (__attribute__((address_space(3))) void*)l, 16, 0, 0);
}

__device__ __forceinline__ u32 lds_off(const void* p) {
  return (u32)(uintptr_t)(__attribute__((address_space(3))) const void*)p;
}

// f32 [Z][512][512] -> bf16 [Z][512][512] transposed (used for Ws only now)
__global__ void transpose_cast(const float* __restrict__ src, u16* __restrict__ dst) {
  __shared__ float tile[32][33];
  const int tx = threadIdx.x, ty = threadIdx.y;
  const int a0 = blockIdx.x * 32;
  const int b0 = blockIdx.y * 32;
  const size_t zoff = (size_t)blockIdx.z * (512 * 512);
  const float* s = src + zoff;
  u16* d = dst + zoff;
#pragma unroll
  for (int r = 0; r < 4; ++r)
    tile[ty + r * 8][tx] = s[(size_t)(a0 + ty + r * 8) * 512 + b0 + tx];
  __syncthreads();
#pragma unroll
  for (int r = 0; r < 4; ++r)
    d[(size_t)(b0 + ty + r * 8) * 512 + a0 + tx] = f2bf(tile[tx][ty + r * 8]);
}

__global__ void zero_k(int* __restrict__ cnt) {
  const int t = blockIdx.x * 256 + threadIdx.x;
  if (t < 5001) cnt[t] = 0;
}

// cd[t] = {col, bits(diag)}; bucket instance t into list[row]
__global__ void fill_k(const int* __restrict__ ev, const float* __restrict__ ui,
                       int2* __restrict__ cd, int* __restrict__ cnt,
                       int* __restrict__ list, int* __restrict__ ovf) {
  const int t = blockIdx.x * 256 + threadIdx.x;  // 0..32767
  const int r = ev[t] - 1;
  int2 v;
  v.x = r;
  v.y = __float_as_int(ui[(size_t)r * (T_ + 1)]);
  cd[t] = v;
  const int pos = atomicAdd(&cnt[r], 1);
  if (pos < CAP) list[r * CAP + pos] = t;
  else { const int o = atomicAdd(&cnt[5000], 1); ovf[o] = t; }
}

// one block per distinct ui row: stage row in LDS, serve instances (2-way ILP)
__global__ __launch_bounds__(256)
void grow_gather(const float* __restrict__ ui, const int2* __restrict__ cd,
                 const int* __restrict__ cnt, const int* __restrict__ list,
                 u16* __restrict__ adj) {
  const int r = blockIdx.x;
  int c = cnt[r];
  if (c <= 0) return;
  if (c > CAP) c = CAP;
  __shared__ float row[5000];
  const float* __restrict__ src = ui + (size_t)r * T_;
  for (int t = threadIdx.x; t < 1250; t += 256)
    *(float4*)&row[t * 4] = *(const float4*)&src[t * 4];
  __syncthreads();
  const int j = threadIdx.x * 2;
  const int lb = r * CAP;
  int q = 0;
  for (; q + 2 <= c; q += 2) {
    const int t0 = list[lb + q], t1 = list[lb + q + 1];
    const int b0 = (t0 >> 9) << 9, b1 = (t1 >> 9) << 9;
    const int4 p0 = *(const int4*)&cd[b0 + j];
    const int4 p1 = *(const int4*)&cd[b1 + j];
    const u32 pk0 = (u32)f2bf(row[p0.x] + __int_as_float(p0.y)) |
                    ((u32)f2bf(row[p0.z] + __int_as_float(p0.w)) << 16);
    const u32 pk1 = (u32)f2bf(row[p1.x] + __int_as_float(p1.y)) |
                    ((u32)f2bf(row[p1.z] + __int_as_float(p1.w)) << 16);
    *(u32*)&adj[(size_t)t0 * 512 + j] = pk0;
    *(u32*)&adj[(size_t)t1 * 512 + j] = pk1;
  }
  if (q < c) {
    const int t0 = list[lb + q];
    const int b0 = (t0 >> 9) << 9;
    const int4 p0 = *(const int4*)&cd[b0 + j];
    const u32 pk0 = (u32)f2bf(row[p0.x] + __int_as_float(p0.y)) |
                    ((u32)f2bf(row[p0.z] + __int_as_float(p0.w)) << 16);
    *(u32*)&adj[(size_t)t0 * 512 + j] = pk0;
  }
}

__global__ void ovf_gather(const float* __restrict__ ui, const int2* __restrict__ cd,
                           const int* __restrict__ cnt, const int* __restrict__ ovf,
                           u16* __restrict__ adj) {
  const int n = cnt[5000];
  for (int q = blockIdx.x; q < n; q += gridDim.x) {
    const int t = ovf[q];
    const int base = (t >> 9) << 9;
    const long r = (long)cd[t].x;
    const float* __restrict__ row = ui + r * (long)T_;
    const int j = threadIdx.x * 2;
    const int4 p = *(const int4*)&cd[base + j];
    const u32 pk = (u32)f2bf(row[p.x] + __int_as_float(p.y)) |
                   ((u32)f2bf(row[p.z] + __int_as_float(p.w)) << 16);
    *(u32*)&adj[(size_t)t * 512 + j] = pk;
  }
}

// ---------------------------------------------------------------------------
// 256x256-tile GEMM, BK=32, 8 waves (2Mx4N), wave tile 128x64.
// BSRC 0: B bf16 n-major [n][k] via gload_lds, 4 LDS B-buffers (R4 path).
// BSRC 1: B f32 k-major [k][n] (enc direct): reg-staged asm loads + cvt_pk +
//         swizzled ds_write_b128 into a single 16KB n-major B buffer.
// MODE 0: C row-major bf16. MODE 1: C transposed + relu. MODE 2: relu+col-sum
// partials P[b][slot][d].
// LDS swizzle (involution): tile byte (row, kb) at (row>>1)*128 +
//   ((((row&1)<<6)|kb) ^ (((row>>1)&7)<<4)).
// ---------------------------------------------------------------------------
template <int MODE, int BSRC>
__global__ __launch_bounds__(512, 2)
void gemm256(const u16* __restrict__ A, const void* __restrict__ Bv,
             u16* __restrict__ C, size_t strideA, size_t strideB, size_t strideC,
             float* __restrict__ P) {
  extern __shared__ u16 smem[];  // A: 4 x 16KB @ [0,64K); B: @ [64K, ...)
  const int tid = threadIdx.x;
  const int lane = tid & 63;
  const int w = tid >> 6;
  const int wm = w >> 2, wn = w & 3;
  const int chunk = gridDim.x >> 3;
  const int wg = blockIdx.x;
  const int mapped = (wg & 7) * chunk + (wg >> 3);
  const int batch = mapped >> 2;
  const int tm = (mapped >> 1) & 1, tn = mapped & 1;
  const int m0 = tm << 8, n0 = tn << 8;
  const u16* __restrict__ Ab = A + (size_t)batch * strideA;

  // A staging: chunk c = r*512+tid (16B); inverse-swizzle to tile coords
  const u16* gA[2];
  u32 ldA[2];
#pragma unroll
  for (int r = 0; r < 2; ++r) {
    const int c = r * 512 + tid;
    const int L = c * 16;
    const int pp = L >> 7;
    const int off = (L & 127) ^ ((pp & 7) << 4);
    const int m = pp * 2 + (off >> 6);
    const int kb = off & 63;
    gA[r] = Ab + (size_t)(m0 + m) * 512 + (kb >> 1);
    ldA[r] = (u32)((r * 512 + w * 64) * 8);  // u16 elems; +lane*16B by HW
  }

  // BSRC0 staging state
  const u16* gB[2] = {nullptr, nullptr};
  u32 ldB[2] = {0, 0};
  if (BSRC == 0) {
    const u16* __restrict__ Bb = (const u16*)Bv + (size_t)batch * strideB;
#pragma unroll
    for (int r = 0; r < 2; ++r) {
      const int c = r * 512 + tid;
      const int L = c * 16;
      const int pp = L >> 7;
      const int off = (L & 127) ^ ((pp & 7) << 4);
      const int m = pp * 2 + (off >> 6);
      const int kb = off & 63;
      gB[r] = Bb + (size_t)(n0 + m) * 512 + (kb >> 1);
      ldB[r] = (u32)(32768 + (r * 512 + w * 64) * 8);
    }
  }

  // BSRC1 staging state: 8 l x 2 d per thread
  const int dp = tid & 127;           // (w&1)*64 + lane
  const int lq = tid >> 7;            // l-quarter (== w>>1)
  unsigned long long encB = 0;
  u32 boff0 = 0;
  u32x2 bs0[8], bs1[8];
  if (BSRC == 1) {
    encB = (unsigned long long)(uintptr_t)((const float*)Bv + (size_t)batch * strideB);
    boff0 = (u32)(((lq * 8) * 512 + n0 + dp * 2) * 4);
  }

#define BLOAD(t, S)                                                          \
  {                                                                          \
    const u32 ob = boff0 + (u32)(t) * 65536u;                                \
    _Pragma("unroll") for (int i = 0; i < 8; ++i)                            \
        asm volatile("global_load_dwordx2 %0, %1, %2"                        \
                     : "=v"(S[i])                                            \
                     : "v"(ob + (u32)i * 2048u), "s"(encB));                 \
  }

#define CONVERT_B(S)                                                         \
  {                                                                          \
    u32 wrd0[4], wrd1[4];                                                    \
    _Pragma("unroll") for (int jj = 0; jj < 4; ++jj) {                       \
      asm("v_cvt_pk_bf16_f32 %0, %1, %2"                                     \
          : "=v"(wrd0[jj]) : "v"(S[2 * jj].x), "v"(S[2 * jj + 1].x));        \
      asm("v_cvt_pk_bf16_f32 %0, %1, %2"                                     \
          : "=v"(wrd1[jj]) : "v"(S[2 * jj].y), "v"(S[2 * jj + 1].y));        \
    }                                                                        \
    const u32 by0 = (u32)dp * 128u + ((((u32)lq * 16u)) ^ (((u32)dp & 7u) << 4)); \
    const u32 by1 = (u32)dp * 128u + ((64u | ((u32)lq * 16u)) ^ (((u32)dp & 7u) << 4)); \
    u32x4 v0, v1;                                                            \
    v0.x = wrd0[0]; v0.y = wrd0[1]; v0.z = wrd0[2]; v0.w = wrd0[3];          \
    v1.x = wrd1[0]; v1.y = wrd1[1]; v1.z = wrd1[2]; v1.w = wrd1[3];          \
    *(u32x4*)((char*)smem + 65536 + by0) = v0;                               \
    *(u32x4*)((char*)smem + 65536 + by1) = v1;                               \
  }

  // frag LDS byte offsets
  const int lr = lane & 15;
  const int kb = (lane >> 4) << 4;
  u32 aOff[8], bOff[4];
#pragma unroll
  for (int m = 0; m < 8; ++m) {
    const int row = wm * 128 + m * 16 + lr;
    aOff[m] = (u32)((row >> 1) * 128 + ((((row & 1) << 6) | kb) ^ (((row >> 1) & 7) << 4)));
  }
#pragma unroll
  for (int n = 0; n < 4; ++n) {
    const int row = wn * 64 + n * 16 + lr;
    bOff[n] = (u32)(65536 + (row >> 1) * 128 + ((((row & 1) << 6) | kb) ^ (((row >> 1) & 7) << 4)));
  }
  const u32 ldsBase = lds_off(smem);

  f32x4 acc[8][4] = {};

  auto stageA = [&](int t) {
    const u32 bo = (u32)(t & 3) * 8192;
#pragma unroll
    for (int r = 0; r < 2; ++r) gload_lds16(gA[r] + t * 32, smem + bo + ldA[r]);
  };
  auto stageB0 = [&](int t) {
    const u32 bo = (u32)(t & 3) * 8192;
#pragma unroll
    for (int r = 0; r < 2; ++r) gload_lds16(gB[r] + t * 32, smem + bo + ldB[r]);
  };

  if (BSRC == 0) {
    stageA(0); stageB0(0); stageA(1); stageB0(1); stageA(2); stageB0(2);
  } else {
    stageA(0); stageA(1); stageA(2);
    BLOAD(0, bs0); BLOAD(1, bs1);
  }

#pragma unroll
  for (int t = 0; t < 16; ++t) {
    if (BSRC == 0) {
      if (t <= 13)      asm volatile("s_waitcnt vmcnt(8)" ::: "memory");
      else if (t == 14) asm volatile("s_waitcnt vmcnt(4)" ::: "memory");
      else              asm volatile("s_waitcnt vmcnt(0)" ::: "memory");
      __builtin_amdgcn_sched_barrier(0);
      if (t + 3 < 16) { stageA(t + 3); stageB0(t + 3); }
      asm volatile("" ::: "memory");
      __builtin_amdgcn_s_barrier();  // B1
      asm volatile("" ::: "memory");
    } else {
      if (t == 0)              asm volatile("s_waitcnt vmcnt(8)" ::: "memory");
      else if (t <= 13)        asm volatile("s_waitcnt vmcnt(10)" ::: "memory");
      else if (t == 14)        asm volatile("s_waitcnt vmcnt(8)" ::: "memory");
      else                     asm volatile("s_waitcnt vmcnt(0)" ::: "memory");
      __builtin_amdgcn_sched_barrier(0);
      // convert tile t (slot t&1) into the single n-major B buffer
      if (t & 1) { CONVERT_B(bs1); } else { CONVERT_B(bs0); }
      // issue next stages
      if (t + 3 < 16) stageA(t + 3);
      if (t + 2 < 16) { if (t & 1) { BLOAD(t + 2, bs1); } else { BLOAD(t + 2, bs0); } }
      asm volatile("s_waitcnt lgkmcnt(0)" ::: "memory");  // drain my ds_writes
      __builtin_amdgcn_s_barrier();  // B1: A(t) landed + all conversions visible
      asm volatile("" ::: "memory");
    }

    const u32 abase = ldsBase + (u32)(t & 3) * 16384;
    const u32 bbase = (BSRC == 0) ? (ldsBase + (u32)(t & 3) * 16384) : ldsBase;
    i32x4 araw[8], braw[4];
#pragma unroll
    for (int m = 0; m < 8; ++m)
      asm volatile("ds_read_b128 %0, %1" : "=v"(araw[m]) : "v"(abase + aOff[m]));
#pragma unroll
    for (int n = 0; n < 4; ++n)
      asm volatile("ds_read_b128 %0, %1" : "=v"(braw[n]) : "v"(bbase + bOff[n]));
    asm volatile("s_waitcnt lgkmcnt(0)" ::: "memory");
    __builtin_amdgcn_sched_barrier(0);

    __builtin_amdgcn_s_setprio(1);
#pragma unroll
    for (int m = 0; m < 8; ++m)
#pragma unroll
      for (int n = 0; n < 4; ++n)
        acc[m][n] = __builtin_amdgcn_mfma_f32_16x16x32_bf16(
            __builtin_bit_cast(bf16x8, araw[m]),
            __builtin_bit_cast(bf16x8, braw[n]), acc[m][n], 0, 0, 0);
    __builtin_amdgcn_s_setprio(0);
    asm volatile("" ::: "memory");
    __builtin_amdgcn_s_barrier();  // B2
    __builtin_amdgcn_sched_barrier(0);
  }
#undef BLOAD
#undef CONVERT_B

  u16* Cb = C + (size_t)batch * strideC;
  if (MODE == 0) {
#pragma unroll
    for (int m = 0; m < 8; ++m) {
      const int row = m0 + wm * 128 + m * 16 + (lane >> 4) * 4;
#pragma unroll
      for (int n = 0; n < 4; ++n) {
        const int col = n0 + wn * 64 + n * 16 + (lane & 15);
        const f32x4 v = acc[m][n];
#pragma unroll
        for (int j = 0; j < 4; ++j)
          Cb[(size_t)(row + j) * 512 + col] = f2bf(v[j]);
      }
    }
  } else if (MODE == 1) {
#pragma unroll
    for (int m = 0; m < 8; ++m) {
      const int i = m0 + wm * 128 + m * 16 + (lane >> 4) * 4;
#pragma unroll
      for (int n = 0; n < 4; ++n) {
        const int d = n0 + wn * 64 + n * 16 + (lane & 15);
        const f32x4 v = acc[m][n];
        uint2 p;
        p.x = (u32)f2bf(fmaxf(v[0], 0.f)) | ((u32)f2bf(fmaxf(v[1], 0.f)) << 16);
        p.y = (u32)f2bf(fmaxf(v[2], 0.f)) | ((u32)f2bf(fmaxf(v[3], 0.f)) << 16);
        *(uint2*)&Cb[(size_t)d * 512 + i] = p;
      }
    }
  } else {
    const int slot = tm * 2 + wm;
#pragma unroll
    for (int n = 0; n < 4; ++n) {
      float s = 0.f;
#pragma unroll
      for (int m = 0; m < 8; ++m) {
        const f32x4 v = acc[m][n];
#pragma unroll
        for (int j = 0; j < 4; ++j) s += fmaxf(v[j], 0.f);
      }
      s += __shfl_xor(s, 16);
      s += __shfl_xor(s, 32);
      if ((lane >> 4) == 0) {
        const int d = n0 + wn * 64 + n * 16 + lane;
        P[((size_t)batch * 4 + slot) * 512 + d] = s;
      }
    }
  }
}

// out[b,d] = (1/512) * sum_slot P[b][slot][d]
__global__ void reduce_mean(const float* __restrict__ P, float* __restrict__ out) {
  const int t = blockIdx.x * 256 + threadIdx.x;
  const int b = t >> 9, d = t & 511;
  float s = 0.f;
#pragma unroll
  for (int q = 0; q < 4; ++q) s += P[((size_t)b * 4 + q) * 512 + d];
  out[t] = s * (1.0f / 512.0f);
}

extern "C" void kernel_launch(void* const* d_in, const int* in_sizes, int n_in,
                              void* d_out, int out_size, void* d_ws, size_t ws_size,
                              hipStream_t stream) {
  const float* enc = (const float*)d_in[0];   // (64,512,512) f32, [l][d] = k-major
  const float* ui  = (const float*)d_in[1];   // (5000,5000) f32
  const float* Ws  = (const float*)d_in[2];   // (2,512,512) f32
  const int*   ev  = (const int*)d_in[3];     // (64,512) int
  float* out = (float*)d_out;                 // (64,512) f32

  char* ws = (char*)d_ws;
  const size_t SLAB = (size_t)64 * 512 * 512 * 2;  // 32 MiB
  u16* adj  = (u16*)(ws);
  u16* tbuf = (u16*)(ws + SLAB);
  u16* xb   = (u16*)(ws + 2 * SLAB);
  char* p = ws + 3 * SLAB;
  u16* wst  = (u16*)p;  p += (size_t)2 * 512 * 512 * 2;
  int2* cd  = (int2*)p; p += (size_t)32768 * 8;
  int* cnt  = (int*)p;  p += 5008 * 4;
  int* list = (int*)p;  p += (size_t)5000 * CAP * 4;
  int* ovf  = (int*)p;  p += (size_t)32768 * 4;
  float* P  = (float*)p;                               // [64][4][512] f32

  const size_t PS = (size_t)512 * 512;
  const size_t SMEM0 = 131072;  // BSRC0: A 4x16K + B 4x16K
  const size_t SMEM1 = 81920;   // BSRC1: A 4x16K + B 1x16K
  (void)hipFuncSetAttribute(reinterpret_cast<const void*>(gemm256<0, 1>),
                            hipFuncAttributeMaxDynamicSharedMemorySize, (int)SMEM1);
  (void)hipFuncSetAttribute(reinterpret_cast<const void*>(gemm256<1, 0>),
                            hipFuncAttributeMaxDynamicSharedMemorySize, (int)SMEM0);
  (void)hipFuncSetAttribute(reinterpret_cast<const void*>(gemm256<0, 0>),
                            hipFuncAttributeMaxDynamicSharedMemorySize, (int)SMEM0);
  (void)hipFuncSetAttribute(reinterpret_cast<const void*>(gemm256<2, 0>),
                            hipFuncAttributeMaxDynamicSharedMemorySize, (int)SMEM0);

  zero_k<<<20, 256, 0, stream>>>(cnt);
  fill_k<<<128, 256, 0, stream>>>(ev, ui, cd, cnt, list, ovf);
  transpose_cast<<<dim3(16, 16, 2), dim3(32, 8), 0, stream>>>(Ws, wst);
  grow_gather<<<5000, 256, 0, stream>>>(ui, cd, cnt, list, adj);
  ovf_gather<<<8, 256, 0, stream>>>(ui, cd, cnt, ovf, adj);
  // layer 0: t = adj @ enc  (B = f32 k-major enc, fused cast)
  gemm256<0, 1><<<256, 512, SMEM1, stream>>>(adj, enc, tbuf, PS, PS, PS, nullptr);
  gemm256<1, 0><<<256, 512, SMEM0, stream>>>(tbuf, wst, xb, PS, 0, PS, nullptr);
  // layer 1 (+ fused mean partials)
  gemm256<0, 0><<<256, 512, SMEM0, stream>>>(adj, xb, tbuf, PS, PS, PS, nullptr);
  gemm256<2, 0><<<256, 512, SMEM0, stream>>>(tbuf, wst + PS, nullptr, PS, 0, 0, P);
  reduce_mean<<<128, 256, 0, stream>>>(P, out);
}